// Round 1
// baseline (14742.909 us; speedup 1.0000x reference)
//
#include <hip/hip_runtime.h>

// ---------------------------------------------------------------------------
// SimpleGRU on MI355X.
// Strategy: bf16 MFMA everywhere (threshold is bf16-scale).
//  - prep kernels: transpose+cast weights to bf16 [col][k] layout in ws,
//    cast inputs to bf16, init h buffer + barrier counters.
//  - gru_main: persistent 256-WG kernel (1 WG/CU, LDS-bound).
//    Partition: 4 batch-groups (32 rows) x 64 col-slices (16 cols/matrix).
//    Recurrent weights + W_x slices in LDS. Per step: phase A (R,Z),
//    row-group flag barrier, phase B (h~ and h update). x-projections for
//    step t+1 computed during barrier-wait slots.
// ---------------------------------------------------------------------------

typedef __attribute__((ext_vector_type(8))) short short8;
typedef __attribute__((ext_vector_type(4))) float f32x4;
typedef __attribute__((ext_vector_type(4))) unsigned short us4;
typedef unsigned short u16;

// ws layout (bytes)
#define OFF_WH  0ul                 // 3 x [1024][1024] bf16 (transposed: Wt[c][k])
#define WH_SZ   2097152ul
#define OFF_WX  6291456ul           // 3 x [1024][512] bf16 (transposed)
#define WX_SZ   1048576ul
#define OFF_XB  9437184ul           // inputs bf16 [128*512][512]
#define OFF_HB  76546048ul          // h bf16 double buffer [2][128][1024]
#define OFF_RH  77070336ul          // Rh bf16 [128][1024]
#define OFF_CNT 77332480ul          // 4 barrier counters, 128B apart
#define WS_NEED 77332992ul

__device__ __forceinline__ u16 f2bf(float f) {
  unsigned u = __float_as_uint(f);
  u += 0x7FFFu + ((u >> 16) & 1u);      // round-to-nearest-even
  return (u16)(u >> 16);
}
__device__ __forceinline__ float sigm(float x) { return 1.f / (1.f + __expf(-x)); }
__device__ __forceinline__ float tanh_f(float x) {
  float e = __expf(2.f * x);
  return 1.f - 2.f / (e + 1.f);
}

// ---- prep: transpose + cast the 6 weight matrices to bf16 Wt[c][k] ----
__global__ __launch_bounds__(256) void prep_wt(
    const float* __restrict__ Whr, const float* __restrict__ Whz,
    const float* __restrict__ Whh, const float* __restrict__ Wxr,
    const float* __restrict__ Wxz, const float* __restrict__ Wxh,
    unsigned char* __restrict__ ws) {
  __shared__ u16 tile[32][36];
  int id = blockIdx.x;
  const float* src; u16* dst; int K, tk, tc;
  if (id < 3072) {                       // W_h: 3 mats, 32x32 tiles of [1024][1024]
    int m = id >> 10, r = id & 1023;
    src = (m == 0) ? Whr : (m == 1) ? Whz : Whh;
    dst = (u16*)(ws + OFF_WH + (size_t)m * WH_SZ);
    K = 1024; tk = r >> 5; tc = r & 31;
  } else {                               // W_x: 3 mats, tiles of [512][1024]
    int r2 = id - 3072;
    int m = r2 >> 9, r = r2 & 511;
    src = (m == 0) ? Wxr : (m == 1) ? Wxz : Wxh;
    dst = (u16*)(ws + OFF_WX + (size_t)m * WX_SZ);
    K = 512; tk = r >> 5; tc = r & 31;
  }
  int t = threadIdx.x;
  int rr = t >> 3, c4 = (t & 7) * 4;
  const float* sp = src + (size_t)(tk * 32 + rr) * 1024 + tc * 32 + c4;
  tile[rr][c4 + 0] = f2bf(sp[0]);
  tile[rr][c4 + 1] = f2bf(sp[1]);
  tile[rr][c4 + 2] = f2bf(sp[2]);
  tile[rr][c4 + 3] = f2bf(sp[3]);
  __syncthreads();
  int rw = t >> 3, k4 = (t & 7) * 4;
  us4 o = { tile[k4 + 0][rw], tile[k4 + 1][rw], tile[k4 + 2][rw], tile[k4 + 3][rw] };
  *(us4*)(dst + (size_t)(tc * 32 + rw) * K + tk * 32 + k4) = o;
}

// ---- prep: cast inputs fp32 -> bf16 ----
__global__ __launch_bounds__(256) void prep_x(const float* __restrict__ xin,
                                              unsigned char* __restrict__ ws) {
  size_t id = (size_t)blockIdx.x * 256 + threadIdx.x;
  const float4* s = (const float4*)xin;
  float4 v = s[id];
  us4 o = { f2bf(v.x), f2bf(v.y), f2bf(v.z), f2bf(v.w) };
  *((us4*)(ws + OFF_XB) + id) = o;
}

// ---- prep: h_prev -> bf16 buf[1]; zero barrier counters ----
__global__ __launch_bounds__(256) void prep_state(const float* __restrict__ hprev,
                                                  unsigned char* __restrict__ ws) {
  int id = blockIdx.x * 256 + threadIdx.x;   // 0..32767 (128 blocks)
  const float4* s = (const float4*)hprev;
  float4 v = s[id];
  us4 o = { f2bf(v.x), f2bf(v.y), f2bf(v.z), f2bf(v.w) };
  *((us4*)(ws + OFF_HB) + 32768 + id) = o;   // buf[1]
  if (blockIdx.x == 0 && threadIdx.x < 128)
    ((unsigned*)(ws + OFF_CNT))[threadIdx.x] = 0u;
}

// ---- main persistent GRU kernel ----
__global__ __launch_bounds__(256, 1) void gru_main(
    const float* __restrict__ hprev, const float* __restrict__ br_g,
    const float* __restrict__ bz_g, const float* __restrict__ bh_g,
    float* __restrict__ out, unsigned char* __restrict__ ws) {
  // LDS: W_h slices 3*[16 cols][1032 k] + W_x slices 3*[16][520] + reduce scratch
  __shared__ short wlds[74496];   // 148,992 B
  __shared__ float red[3072];     //  12,288 B  (total 161,280 < 160 KiB)

  const u16* __restrict__ xb = (const u16*)(ws + OFF_XB);
  u16* hb = (u16*)(ws + OFF_HB);
  u16* rhb = (u16*)(ws + OFF_RH);
  unsigned* cnt = (unsigned*)(ws + OFF_CNT);

  const int bid = blockIdx.x;
  const int gi = bid & 3;          // batch group: rows [32*gi, 32*gi+32)
  const int gj = bid >> 2;         // col group: cols [16*gj, 16*gj+16) per matrix
  const int tid = threadIdx.x;
  const int w = tid >> 6;          // wave 0..3
  const int l = tid & 63;
  const int ln = l & 15;           // MFMA n / C-col index
  const int lq = l >> 4;           // MFMA k-octet / C-row-quad
  const int mt = w & 1;            // M-tile (16 rows)
  const int kh = w >> 1;           // K-half; waves 0,1 = owners, 2,3 = helpers
  const bool owner = (w < 2);

  // ---- stage weight slices into LDS (once) ----
  for (int m = 0; m < 3; m++) {
    const u16* src = (const u16*)(ws + OFF_WH + (size_t)m * WH_SZ) + (size_t)gj * 16 * 1024;
    short* dst = wlds + m * 16512;
    #pragma unroll
    for (int it = 0; it < 8; it++) {
      int idx = it * 256 + tid;
      int c = idx >> 7, oc = idx & 127;
      *(short8*)(dst + c * 1032 + oc * 8) = *(const short8*)(src + c * 1024 + oc * 8);
    }
  }
  for (int m = 0; m < 3; m++) {
    const u16* src = (const u16*)(ws + OFF_WX + (size_t)m * WX_SZ) + (size_t)gj * 16 * 512;
    short* dst = wlds + 49536 + m * 8320;
    #pragma unroll
    for (int it = 0; it < 4; it++) {
      int idx = it * 256 + tid;
      int c = idx >> 6, oc = idx & 63;
      *(short8*)(dst + c * 520 + oc * 8) = *(const short8*)(src + c * 512 + oc * 8);
    }
  }
  __syncthreads();

  const int cg = gj * 16 + ln;                 // owned output column
  const int rb = gi * 32 + mt * 16 + lq * 4;   // owned C-rows base (owners)
  const int bA = gi * 32 + mt * 16 + ln;       // A-fragment row (m = lane&15)
  const float brv = br_g[cg], bzv = bz_g[cg], bhv = bh_g[cg];

  f32x4 hloc = {0.f, 0.f, 0.f, 0.f};
  if (owner) {
    #pragma unroll
    for (int r = 0; r < 4; r++) hloc[r] = hprev[(size_t)(rb + r) * 1024 + cg];
  }

  f32x4 xr_p = {0,0,0,0}, xz_p = {0,0,0,0}, xh_p = {0,0,0,0};
  f32x4 Zv = {0,0,0,0};

  // x-projection for step t: xr/xz partials (red[1024:2048)), xh (red[2048:2560))
  auto xproj_rz = [&](int t) {
    f32x4 ar = {0,0,0,0}, az = {0,0,0,0};
    const u16* abase = xb + (size_t)bA * 262144 + (size_t)t * 512 + kh * 256 + lq * 8;
    const short* wr = wlds + 49536 + 0 * 8320 + ln * 520 + kh * 256 + lq * 8;
    const short* wz = wlds + 49536 + 1 * 8320 + ln * 520 + kh * 256 + lq * 8;
    #pragma unroll
    for (int kk = 0; kk < 8; kk++) {
      short8 a = *(const short8*)(abase + kk * 32);
      short8 b1 = *(const short8*)(wr + kk * 32);
      short8 b2 = *(const short8*)(wz + kk * 32);
      ar = __builtin_amdgcn_mfma_f32_16x16x32_bf16(a, b1, ar, 0, 0, 0);
      az = __builtin_amdgcn_mfma_f32_16x16x32_bf16(a, b2, az, 0, 0, 0);
    }
    if (!owner) {
      #pragma unroll
      for (int r = 0; r < 4; r++) {
        red[1024 + (mt * 2 + 0) * 256 + l * 4 + r] = ar[r];
        red[1024 + (mt * 2 + 1) * 256 + l * 4 + r] = az[r];
      }
    } else { xr_p = ar; xz_p = az; }
  };
  auto xproj_h = [&](int t) {
    f32x4 ah = {0,0,0,0};
    const u16* abase = xb + (size_t)bA * 262144 + (size_t)t * 512 + kh * 256 + lq * 8;
    const short* wh = wlds + 49536 + 2 * 8320 + ln * 520 + kh * 256 + lq * 8;
    #pragma unroll
    for (int kk = 0; kk < 8; kk++) {
      short8 a = *(const short8*)(abase + kk * 32);
      short8 b3 = *(const short8*)(wh + kk * 32);
      ah = __builtin_amdgcn_mfma_f32_16x16x32_bf16(a, b3, ah, 0, 0, 0);
    }
    if (!owner) {
      #pragma unroll
      for (int r = 0; r < 4; r++) red[2048 + mt * 256 + l * 4 + r] = ah[r];
    } else { xh_p = ah; }
  };

  // prologue: x-projection for t=0
  xproj_rz(0);
  xproj_h(0);
  __syncthreads();

  unsigned* myc = cnt + gi * 32;

  for (int t = 0; t < 512; t++) {
    const int pb = (t & 1) ^ 1;                 // h buffer holding h(t-1)
    const int tn = (t < 511) ? (t + 1) : 511;   // next-step x (clamped)

    // ---------------- Phase A: R, Z ----------------
    {
      f32x4 aR = {0,0,0,0}, aZ = {0,0,0,0};
      const u16* abase = hb + (size_t)pb * 131072 + (size_t)bA * 1024 + kh * 512 + lq * 8;
      const short* w1 = wlds + 0 * 16512 + ln * 1032 + kh * 512 + lq * 8;
      const short* w2 = wlds + 1 * 16512 + ln * 1032 + kh * 512 + lq * 8;
      #pragma unroll
      for (int kk = 0; kk < 16; kk++) {
        short8 a = *(const short8*)(abase + kk * 32);
        short8 b1 = *(const short8*)(w1 + kk * 32);
        short8 b2 = *(const short8*)(w2 + kk * 32);
        aR = __builtin_amdgcn_mfma_f32_16x16x32_bf16(a, b1, aR, 0, 0, 0);
        aZ = __builtin_amdgcn_mfma_f32_16x16x32_bf16(a, b2, aZ, 0, 0, 0);
      }
      if (!owner) {
        #pragma unroll
        for (int r = 0; r < 4; r++) {
          red[(mt * 2 + 0) * 256 + l * 4 + r] = aR[r];
          red[(mt * 2 + 1) * 256 + l * 4 + r] = aZ[r];
        }
      }
      __syncthreads();
      if (owner) {
        #pragma unroll
        for (int r = 0; r < 4; r++) {
          float xr = xr_p[r] + red[1024 + (mt * 2 + 0) * 256 + l * 4 + r] + brv;
          float xz = xz_p[r] + red[1024 + (mt * 2 + 1) * 256 + l * 4 + r] + bzv;
          float R = sigm(aR[r] + red[(mt * 2 + 0) * 256 + l * 4 + r] + xr);
          float Z = sigm(aZ[r] + red[(mt * 2 + 1) * 256 + l * 4 + r] + xz);
          Zv[r] = Z;
          rhb[(size_t)(rb + r) * 1024 + cg] = f2bf(R * hloc[r]);
        }
      }
    }
    __syncthreads();                            // drain Rh stores (all waves)
    if (tid == 0) { __threadfence(); atomicAdd(myc, 1u); }
    xproj_rz(tn);                               // overlap barrier wait
    if (tid == 0) {
      unsigned tgt = 64u * (unsigned)(2 * t + 1);
      int g = 0;
      while (__hip_atomic_load(myc, __ATOMIC_RELAXED, __HIP_MEMORY_SCOPE_AGENT) < tgt) {
        __builtin_amdgcn_s_sleep(2);
        if (++g > (1 << 26)) break;             // dead-man guard
      }
      __threadfence();
    }
    __syncthreads();

    // ---------------- Phase B: h~, h update ----------------
    {
      f32x4 aH = {0,0,0,0};
      const u16* abase = rhb + (size_t)bA * 1024 + kh * 512 + lq * 8;
      const short* w3 = wlds + 2 * 16512 + ln * 1032 + kh * 512 + lq * 8;
      #pragma unroll
      for (int kk = 0; kk < 16; kk++) {
        short8 a = *(const short8*)(abase + kk * 32);
        short8 b3 = *(const short8*)(w3 + kk * 32);
        aH = __builtin_amdgcn_mfma_f32_16x16x32_bf16(a, b3, aH, 0, 0, 0);
      }
      if (!owner) {
        #pragma unroll
        for (int r = 0; r < 4; r++) red[mt * 256 + l * 4 + r] = aH[r];
      }
      __syncthreads();
      if (owner) {
        u16* hbw = hb + (size_t)(t & 1) * 131072;
        #pragma unroll
        for (int r = 0; r < 4; r++) {
          float xh = xh_p[r] + red[2048 + mt * 256 + l * 4 + r] + bhv;
          float ht = tanh_f(aH[r] + red[mt * 256 + l * 4 + r] + xh);
          float hn = Zv[r] * ht + (1.f - Zv[r]) * hloc[r];
          hloc[r] = hn;
          hbw[(size_t)(rb + r) * 1024 + cg] = f2bf(hn);
          out[((size_t)(rb + r) * 512 + (size_t)t) * 1024 + cg] = hn;
        }
      }
    }
    __syncthreads();
    if (tid == 0) { __threadfence(); atomicAdd(myc, 1u); }
    xproj_h(tn);                                // overlap barrier wait
    if (tid == 0) {
      unsigned tgt = 64u * (unsigned)(2 * t + 2);
      int g = 0;
      while (__hip_atomic_load(myc, __ATOMIC_RELAXED, __HIP_MEMORY_SCOPE_AGENT) < tgt) {
        __builtin_amdgcn_s_sleep(2);
        if (++g > (1 << 26)) break;
      }
      __threadfence();
    }
    __syncthreads();
  }
}

extern "C" void kernel_launch(void* const* d_in, const int* in_sizes, int n_in,
                              void* d_out, int out_size, void* d_ws, size_t ws_size,
                              hipStream_t stream) {
  const float* inputs = (const float*)d_in[0];
  const float* hprev  = (const float*)d_in[1];
  const float* Whr    = (const float*)d_in[2];
  const float* Wxr    = (const float*)d_in[3];
  const float* br     = (const float*)d_in[4];
  const float* Whz    = (const float*)d_in[5];
  const float* Wxz    = (const float*)d_in[6];
  const float* bz     = (const float*)d_in[7];
  const float* Whh    = (const float*)d_in[8];
  const float* Wxh    = (const float*)d_in[9];
  const float* bh     = (const float*)d_in[10];
  float* out = (float*)d_out;
  unsigned char* ws = (unsigned char*)d_ws;

  prep_wt<<<4608, 256, 0, stream>>>(Whr, Whz, Whh, Wxr, Wxz, Wxh, ws);
  prep_x<<<32768, 256, 0, stream>>>(inputs, ws);
  prep_state<<<128, 256, 0, stream>>>(hprev, ws);
  gru_main<<<256, 256, 0, stream>>>(hprev, br, bz, bh, out, ws);
}